// Round 4
// baseline (42.558 us; speedup 1.0000x reference)
//
#include <hip/hip_runtime.h>
#include <math.h>

#define KNBR 20
#define BLK  256
#define APB  32           // atoms per block in K1 (BLK/8)

#define THETA_T  1.9106332362490186f   // 0.6081734479693927 * pi
#define INV_SIG  4.7746482927568605f   // 1 / (12 deg in rad)
#define PI_F     3.14159265358979323846f

// ---------------- Kernel 1: SH (q2,q4,q6) + cn + compacted unit vectors ----
__global__ __launch_bounds__(BLK)
void k_sh(const float* __restrict__ pos,
          const int*   __restrict__ aidx,
          const int*   __restrict__ nidx,
          const int*   __restrict__ vmsk,
          float*       __restrict__ out,
          float4*      __restrict__ uws,
          int M)
{
    const int tid   = threadIdx.x;
    const int r     = tid & 7;              // lane within octet
    const int al    = tid >> 3;             // atom-local 0..31
    const int i     = blockIdx.x * APB + al;
    if (i >= M) return;
    const int lane  = tid & 63;
    const int obase = lane & ~7;

    float cx, cy, cz;
    { const int a = aidx[i]; cx = pos[3*a]; cy = pos[3*a+1]; cz = pos[3*a+2]; }

    // my 3 neighbor slots: r, r+8, and (r<4 ? 16+r : masked)
    const size_t row = (size_t)i * KNBR;
    const int n0 = nidx[row + r];
    const int n1 = nidx[row + r + 8];
    const int n2 = nidx[row + 16 + (r & 3)];
    const int m0 = vmsk[row + r] != 0;
    const int m1 = vmsk[row + r + 8] != 0;
    const int m2 = (r < 4) && (vmsk[row + 16 + (r & 3)] != 0);

    // all 9 gathers issued up-front (overlapped latency)
    const float q0x = pos[3*n0], q0y = pos[3*n0+1], q0z = pos[3*n0+2];
    const float q1x = pos[3*n1], q1y = pos[3*n1+1], q1z = pos[3*n1+2];
    const float q2x = pos[3*n2], q2y = pos[3*n2+1], q2z = pos[3*n2+2];

    // octet exclusive scan + total
    const int cntLoc = m0 + m1 + m2;
    int off = 0, total = 0;
    #pragma unroll
    for (int k = 0; k < 8; ++k) {
        const int c = __shfl(cntLoc, obase + k);
        total += c;
        if (r > k) off += c;
    }

    float re20=0.f, re21=0.f, im21=0.f, re22=0.f, im22=0.f;
    float re40=0.f, re41=0.f, im41=0.f, re42=0.f, im42=0.f;
    float re43=0.f, im43=0.f, re44=0.f, im44=0.f;
    float re60=0.f, re61=0.f, im61=0.f, re62=0.f, im62=0.f;
    float re63=0.f, im63=0.f, re64=0.f, im64=0.f;
    float re65=0.f, im65=0.f, re66=0.f, im66=0.f;

    float4* myrow = uws + (size_t)i * KNBR;

    auto sh = [&](float px, float py, float pz, int mi) {
        const float mk = (float)mi;
        const float vx = px - cx, vy = py - cy, vz = pz - cz;
        const float d2 = fmaf(vx, vx, fmaf(vy, vy, vz * vz));
        const float inv = __builtin_amdgcn_rcpf(sqrtf(d2) + 1e-10f);
        const float ux = vx * inv, uy = vy * inv, uz = vz * inv;

        if (mi) myrow[off] = make_float4(ux, uy, uz, 0.f);
        off += mi;

        const float x = uz, x2 = x * x;
        // w_m = (ux + i uy)^m  (masked: kills all m>=1 terms when invalid)
        const float w1r = ux * mk, w1i = uy * mk;
        const float w2r = fmaf(w1r, w1r, -(w1i * w1i)), w2i = 2.f * (w1r * w1i);
        const float w3r = fmaf(w2r, w1r, -(w2i * w1i)), w3i = fmaf(w2r, w1i, w2i * w1r);
        const float w4r = fmaf(w3r, w1r, -(w3i * w1i)), w4i = fmaf(w3r, w1i, w3i * w1r);
        const float w5r = fmaf(w4r, w1r, -(w4i * w1i)), w5i = fmaf(w4r, w1i, w4i * w1r);
        const float w6r = fmaf(w5r, w1r, -(w5i * w1i)), w6i = fmaf(w5r, w1i, w5i * w1r);

        float P;
        // m = 0  (needs explicit mask)
        P = fmaf(0.94617470f, x2, -0.31539157f);
        re20 = fmaf(P, mk, re20);
        P = fmaf(fmaf(3.70249414f, x2, -3.17356641f), x2, 0.31735664f);
        re40 = fmaf(P, mk, re40);
        P = fmaf(fmaf(fmaf(14.6844843f, x2, -20.0242968f), x2, 6.67476559f), x2, -0.31784598f);
        re60 = fmaf(P, mk, re60);
        // m = 1
        P = -0.77254840f * x;
        re21 = fmaf(P, w1r, re21); im21 = fmaf(P, w1i, im21);
        P = x * fmaf(-3.31161144f, x2, 1.41926204f);
        re41 = fmaf(P, w1r, re41); im41 = fmaf(P, w1i, im41);
        P = x * fmaf(fmaf(-13.5951914f, x2, 12.3592649f), x2, -2.05987749f);
        re61 = fmaf(P, w1r, re61); im61 = fmaf(P, w1i, im61);
        // m = 2
        re22 = fmaf(0.38627420f, w2r, re22); im22 = fmaf(0.38627420f, w2i, im22);
        P = fmaf(2.34166290f, x2, -0.33452327f);
        re42 = fmaf(P, w2r, re42); im42 = fmaf(P, w2i, im42);
        P = fmaf(fmaf(10.7479410f, x2, -5.86251329f), x2, 0.32569518f);
        re62 = fmaf(P, w2r, re62); im62 = fmaf(P, w2i, im62);
        // m = 3
        P = -1.25167160f * x;
        re43 = fmaf(P, w3r, re43); im43 = fmaf(P, w3i, im43);
        P = x * fmaf(-7.16529533f, x2, 1.95417145f);
        re63 = fmaf(P, w3r, re63); im63 = fmaf(P, w3i, im63);
        // m = 4
        re44 = fmaf(0.44253269f, w4r, re44); im44 = fmaf(0.44253269f, w4i, im44);
        P = fmaf(3.92459379f, x2, -0.35678125f);
        re64 = fmaf(P, w4r, re64); im64 = fmaf(P, w4i, im64);
        // m = 5
        P = -1.67345246f * x;
        re65 = fmaf(P, w5r, re65); im65 = fmaf(P, w5i, im65);
        // m = 6
        re66 = fmaf(0.48308411f, w6r, re66); im66 = fmaf(0.48308411f, w6i, im66);
    };

    sh(q0x, q0y, q0z, m0);
    sh(q1x, q1y, q1z, m1);
    sh(q2x, q2y, q2z, m2);

#define RED(v) { v += __shfl_xor(v,1); v += __shfl_xor(v,2); v += __shfl_xor(v,4); }
    RED(re20) RED(re21) RED(im21) RED(re22) RED(im22)
    RED(re40) RED(re41) RED(im41) RED(re42) RED(im42)
    RED(re43) RED(im43) RED(re44) RED(im44)
    RED(re60) RED(re61) RED(im61) RED(re62) RED(im62)
    RED(re63) RED(im63) RED(re64) RED(im64)
    RED(re65) RED(im65) RED(re66) RED(im66)
#undef RED

    const float S2 = fmaf(re20, re20,
                     2.f * (fmaf(re21,re21, fmaf(im21,im21, fmaf(re22,re22, im22*im22)))));
    const float S4 = fmaf(re40, re40,
                     2.f * (fmaf(re41,re41, fmaf(im41,im41, fmaf(re42,re42, fmaf(im42,im42,
                            fmaf(re43,re43, fmaf(im43,im43, fmaf(re44,re44, im44*im44)))))))));
    const float S6 = fmaf(re60, re60,
                     2.f * (fmaf(re61,re61, fmaf(im61,im61, fmaf(re62,re62, fmaf(im62,im62,
                            fmaf(re63,re63, fmaf(im63,im63, fmaf(re64,re64, fmaf(im64,im64,
                            fmaf(re65,re65, fmaf(im65,im65, fmaf(re66,re66, im66*im66)))))))))))));

    const float cn = (float)total;
    const float invnb = 1.f / fmaxf(cn, 1.f);
    const float q2v = invnb * sqrtf(2.5132741228718345f * S2);  // 4pi/5
    const float q4v = invnb * sqrtf(1.3962634015954636f * S4);  // 4pi/9
    const float q6v = invnb * sqrtf(0.9666438933772774f * S6);  // 4pi/13

    if      (r == 0) out[0 * M + i] = cn;
    else if (r == 1) out[2 * M + i] = q2v;
    else if (r == 2) out[3 * M + i] = q4v;
    else if (r == 3) out[4 * M + i] = q6v;
}

// ---------------- Kernel 2: tetrahedral OP, one wave per atom --------------
__global__ __launch_bounds__(BLK)
void k_tet(const float4* __restrict__ uws,
           float*        __restrict__ out,
           int M)
{
    const int wid  = blockIdx.x * (BLK / 64) + (threadIdx.x >> 6);
    if (wid >= M) return;
    const int lane = threadIdx.x & 63;

    const float cn = out[wid];                    // written by k_sh (row 0)
    const int   icn = (int)cn;
    const int   npairs = (icn * (icn - 1)) >> 1;
    const float4* row = uws + (size_t)wid * KNBR;

    float gsum = 0.f;
    for (int p = lane; p < npairs; p += 64) {
        const int ja = (int)((1.f + sqrtf(fmaf(8.f, (float)p, 1.5f))) * 0.5f);
        const int ia = p - ((ja * (ja - 1)) >> 1);

        const float4 A = row[ia];
        const float4 B = row[ja];
        float d = fmaf(A.x, B.x, fmaf(A.y, B.y, A.z * B.z));
        d = fminf(fmaxf(d, -0.9999999f), 0.9999999f);

        const float ad = fabsf(d);
        const float pq = fmaf(fmaf(fmaf(-0.0187293f, ad, 0.0742610f), ad, -0.2121144f), ad,
                              1.5707288f) * sqrtf(1.f - ad);
        const float ang = (d >= 0.f) ? pq : PI_F - pq;
        const float t = (ang - THETA_T) * INV_SIG;
        gsum += __expf(-0.5f * t * t);
    }

    gsum += __shfl_xor(gsum, 1);
    gsum += __shfl_xor(gsum, 2);
    gsum += __shfl_xor(gsum, 4);
    gsum += __shfl_xor(gsum, 8);
    gsum += __shfl_xor(gsum, 16);
    gsum += __shfl_xor(gsum, 32);

    if (lane == 0)
        out[M + wid] = (2.f * gsum) / fmaxf(cn * (cn - 1.f), 1.f);
}

extern "C" void kernel_launch(void* const* d_in, const int* in_sizes, int n_in,
                              void* d_out, int out_size, void* d_ws, size_t ws_size,
                              hipStream_t stream) {
    const float* pos  = (const float*)d_in[0];
    const int*   aidx = (const int*)d_in[1];
    const int*   nidx = (const int*)d_in[2];
    const int*   vmsk = (const int*)d_in[3];
    float*  out = (float*)d_out;
    float4* uws = (float4*)d_ws;
    const int M = in_sizes[1];

    const int grid1 = (M + APB - 1) / APB;
    k_sh<<<grid1, BLK, 0, stream>>>(pos, aidx, nidx, vmsk, out, uws, M);

    const int wpb = BLK / 64;
    const int grid2 = (M + wpb - 1) / wpb;
    k_tet<<<grid2, BLK, 0, stream>>>(uws, out, M);
}

// Round 5
// 26.476 us; speedup vs baseline: 1.6075x; 1.6075x over previous
//
#include <hip/hip_runtime.h>
#include <math.h>

#define KNBR 20
#define BLK  256
#define GRP  32              // lanes per atom
#define APB  (BLK / GRP)     // 8 atoms per block

#define THETA_T  1.9106332362490186f   // 0.6081734479693927 * pi
#define INV_SIG  4.7746482927568605f   // 1 / (12 deg in rad)
#define PI_F     3.14159265358979323846f

// Uses the SH addition theorem: sum_m |sum_n Y_lm(u_n)|^2
//   = (2l+1)/(4pi) * sum_{n,n'} P_l(u_n . u_n')
// so q_l = (1/nb) * sqrt(cn + 2 * sum_{i<j} P_l(d_ij)) — the q's share the
// pairwise dot products with the tetrahedral order parameter.
__global__ __launch_bounds__(BLK)
void op_kernel(const float* __restrict__ pos,
               const int*   __restrict__ aidx,
               const int*   __restrict__ nidx,
               const int*   __restrict__ vmsk,
               float*       __restrict__ out,
               int M)
{
    __shared__ float4 su[APB * KNBR];       // 2560 B
    const int tid  = threadIdx.x;
    const int r    = tid & (GRP - 1);       // lane within 32-lane group
    const int al   = tid / GRP;             // atom in block 0..7
    const int i    = blockIdx.x * APB + al;
    if (i >= M) return;
    const int half = (tid & 63) >> 5;       // which 32-half of the wave

    // center position (uniform within group -> broadcast loads)
    const int a = aidx[i];
    const float cx = pos[3 * a], cy = pos[3 * a + 1], cz = pos[3 * a + 2];

    // lane r < 20 owns neighbor slot r
    int valid = 0, nj = 0;
    if (r < KNBR) {
        nj    = nidx[(size_t)i * KNBR + r];
        valid = vmsk[(size_t)i * KNBR + r] != 0;
    }
    const unsigned long long bal = __ballot(valid);
    const unsigned int b32 = (unsigned int)(bal >> (half * 32));
    const int total = __popc(b32);
    const int slot  = __popc(b32 & ((1u << r) - 1u));

    if (valid) {
        const float px = pos[3 * nj], py = pos[3 * nj + 1], pz = pos[3 * nj + 2];
        const float vx = px - cx, vy = py - cy, vz = pz - cz;
        const float d2 = fmaf(vx, vx, fmaf(vy, vy, vz * vz));
        const float inv = __builtin_amdgcn_rcpf(sqrtf(d2) + 1e-10f);
        su[al * KNBR + slot] = make_float4(vx * inv, vy * inv, vz * inv, 0.f);
    }
    // writers and readers are the same wave: DS ops execute in program order,
    // no barrier needed (su row is private to this 32-lane group).

    const int npairs = (total * (total - 1)) >> 1;
    const float4* row = &su[al * KNBR];

    float gsum = 0.f, s2 = 0.f, s4 = 0.f, s6 = 0.f;
    for (int p = r; p < npairs; p += GRP) {
        // triangular decode: 8p+1 is an exact perfect square at boundaries
        const int j  = (int)((1.0f + sqrtf(fmaf(8.f, (float)p, 1.0f))) * 0.5f);
        const int ii = p - ((j * (j - 1)) >> 1);

        const float4 A = row[ii];
        const float4 B = row[j];
        const float d = fmaf(A.x, B.x, fmaf(A.y, B.y, A.z * B.z));

        // Legendre sums for q2/q4/q6 (addition theorem)
        const float e = d * d;
        s2 += fmaf(1.5f, e, -0.5f);
        s4 += fmaf(fmaf(4.375f, e, -3.75f), e, 0.375f);
        s6 += fmaf(fmaf(fmaf(14.4375f, e, -19.6875f), e, 6.5625f), e, -0.3125f);

        // tetrahedral gaussian
        float dc = fminf(fmaxf(d, -0.9999999f), 0.9999999f);
        const float ad = fabsf(dc);
        const float pq = fmaf(fmaf(fmaf(-0.0187293f, ad, 0.0742610f), ad, -0.2121144f), ad,
                              1.5707288f) * sqrtf(1.f - ad);
        const float ang = (dc >= 0.f) ? pq : PI_F - pq;
        const float t = (ang - THETA_T) * INV_SIG;
        gsum += __expf(-0.5f * t * t);
    }

#define RED(v) { v += __shfl_xor(v,1); v += __shfl_xor(v,2); v += __shfl_xor(v,4); \
                 v += __shfl_xor(v,8); v += __shfl_xor(v,16); }
    RED(gsum) RED(s2) RED(s4) RED(s6)
#undef RED

    const float cn = (float)total;
    const float invnb = 1.f / fmaxf(cn, 1.f);

    if      (r == 0) out[0 * M + i] = cn;
    else if (r == 1) out[1 * M + i] = 2.f * gsum / fmaxf(cn * (cn - 1.f), 1.f);
    else if (r == 2) out[2 * M + i] = invnb * sqrtf(fmaxf(fmaf(2.f, s2, cn), 0.f));
    else if (r == 3) out[3 * M + i] = invnb * sqrtf(fmaxf(fmaf(2.f, s4, cn), 0.f));
    else if (r == 4) out[4 * M + i] = invnb * sqrtf(fmaxf(fmaf(2.f, s6, cn), 0.f));
}

extern "C" void kernel_launch(void* const* d_in, const int* in_sizes, int n_in,
                              void* d_out, int out_size, void* d_ws, size_t ws_size,
                              hipStream_t stream) {
    const float* pos  = (const float*)d_in[0];
    const int*   aidx = (const int*)d_in[1];
    const int*   nidx = (const int*)d_in[2];
    const int*   vmsk = (const int*)d_in[3];
    float* out = (float*)d_out;
    const int M = in_sizes[1];
    const int grid = (M + APB - 1) / APB;
    op_kernel<<<grid, BLK, 0, stream>>>(pos, aidx, nidx, vmsk, out, M);
}